// Round 3
// baseline (2642.650 us; speedup 1.0000x reference)
//
#include <hip/hip_runtime.h>
#include <hip/hip_bf16.h>
#include <math.h>

constexpr int B = 32;
constexpr int N = 2048;

// ---------------------------------------------------------------------------
// dtype sniffer: bf16 vs fp32 (validated rounds 1-2).
// ---------------------------------------------------------------------------
__global__ void detect_kernel(const unsigned int* __restrict__ raw, int* __restrict__ flag) {
    __shared__ int cnt;
    if (threadIdx.x == 0) cnt = 0;
    __syncthreads();
    int c = 0;
    for (int i = threadIdx.x; i < 4096; i += 256) {
        unsigned h = (raw[i] >> 8) & 0x7f;
        if (h >= 0x3a && h <= 0x41) c++;
    }
    atomicAdd(&cnt, c);
    __syncthreads();
    if (threadIdx.x == 0) *flag = (cnt > (4096 * 55) / 100) ? 1 : 0;
}

struct ConvSeg { const void* src; float* dst; int n; };
struct ConvParams { ConvSeg s[15]; };

__global__ void convert_kernel(ConvParams p, const int* __restrict__ flag) {
    const ConvSeg sg = p.s[blockIdx.y];
    int i = blockIdx.x * 256 + threadIdx.x;
    if (i >= sg.n) return;
    if (*flag) sg.dst[i] = __bfloat162float(((const __hip_bfloat16*)sg.src)[i]);
    else       sg.dst[i] = ((const float*)sg.src)[i];
}

// ---------------------------------------------------------------------------
// Wave-64 max reduce via DPP (pure VALU): row_shr 1/2/4/8 then row_bcast
// 15/31 -> lane 63 holds the max. Invalid lanes keep old (bound_ctrl=false,
// old = v), so every step is max(v, shifted v).
// ---------------------------------------------------------------------------
#define DPP_MAXF(v, ctrl)                                                      \
    (v) = fmaxf((v), __int_as_float(__builtin_amdgcn_update_dpp(               \
        __float_as_int(v), __float_as_int(v), (ctrl), 0xf, 0xf, false)))

// ---------------------------------------------------------------------------
// FPS phase in LDS. Exact semantics: jnp.argmax (first max index) over fp32
// distances computed with contract(off). Per-iter: fused d-update+scan, DPP
// value reduce, ballot index resolve (lowest lane = lowest index), packed u64
// cross-wave slots (value<<32 | ~idx), one barrier.
// ---------------------------------------------------------------------------
template <int NPTS>
__device__ __forceinline__ void fps_phase(const float* __restrict__ px,
                                          const float* __restrict__ py,
                                          const float* __restrict__ pz,
                                          int* __restrict__ sel_lds,
                                          unsigned long long* __restrict__ slots,
                                          int m, int t) {
    #pragma clang fp contract(off)
    constexpr int P = NPTS / 256;
    float d[P], ox[P], oy[P], oz[P];
    #pragma unroll
    for (int p = 0; p < P; ++p) {
        const int ii = t * P + p;
        ox[p] = px[ii]; oy[p] = py[ii]; oz[p] = pz[ii];
        d[p] = __builtin_inff();     // iteration 1 update vs point 0 == ref init
    }
    if (t == 0) sel_lds[0] = 0;
    float nx = px[0], ny = py[0], nz = pz[0];

    for (int it = 1; it < m; ++it) {
        float bv = -1.0f; int bix = 0;
        #pragma unroll
        for (int p = 0; p < P; ++p) {
            float dx = ox[p] - nx, dy = oy[p] - ny, dz = oz[p] - nz;
            float dd = (dx * dx + dy * dy) + dz * dz;
            float dn = fminf(d[p], dd);
            d[p] = dn;
            if (dn > bv) { bv = dn; bix = t * P + p; }   // strict > keeps lowest idx
        }
        // wave max (value only, VALU DPP chain)
        float r = bv;
        DPP_MAXF(r, 0x111); DPP_MAXF(r, 0x112); DPP_MAXF(r, 0x114);
        DPP_MAXF(r, 0x118); DPP_MAXF(r, 0x142); DPP_MAXF(r, 0x143);
        const float gmax = __int_as_float(__builtin_amdgcn_readlane(__float_as_int(r), 63));
        // index resolve: lowest lane with bv == gmax == lowest global index
        const unsigned long long msk = __ballot(bv == gmax);
        const int wl = (int)__builtin_ctzll(msk);
        const int widx = __builtin_amdgcn_readlane(bix, wl);
        if ((t & 63) == 0) {
            slots[(it & 1) * 4 + (t >> 6)] =
                ((unsigned long long)(unsigned)__float_as_int(gmax) << 32) |
                (unsigned)(~widx);
        }
        __syncthreads();
        const unsigned long long* sp = slots + (it & 1) * 4;
        unsigned long long k0 = sp[0], k1 = sp[1], k2 = sp[2], k3 = sp[3];
        if (k1 > k0) k0 = k1;
        if (k3 > k2) k2 = k3;
        if (k2 > k0) k0 = k2;
        const int g = ~(int)(unsigned)(k0 & 0xffffffffULL);
        if (t == 0) sel_lds[it] = g;
        nx = px[g]; ny = py[g]; nz = pz[g];
    }
    __syncthreads();
}

// ---------------------------------------------------------------------------
// KNN from LDS-staged candidates; lexicographic (d2, idx) == stable top_k.
// Results to nb_l[t + tstride*q] (LDS) for later dynamic-k indexing.
// ---------------------------------------------------------------------------
template <int K>
__device__ __forceinline__ void knn_lds(const float* __restrict__ cx,
                                        const float* __restrict__ cy,
                                        const float* __restrict__ cz,
                                        int n, float xi, float yi, float zi,
                                        int* __restrict__ nb_l, int t, int tstride) {
    #pragma clang fp contract(off)
    float bd[K]; int bi_[K];
    #pragma unroll
    for (int q = 0; q < K; ++q) { bd[q] = __builtin_inff(); bi_[q] = 0x7fffffff; }
    for (int j = 0; j < n; ++j) {
        float dx = xi - cx[j], dy = yi - cy[j], dz = zi - cz[j];
        float d2 = (dx * dx + dy * dy) + dz * dz;
        if (d2 < bd[K - 1] || (d2 == bd[K - 1] && j < bi_[K - 1])) {
            bd[K - 1] = d2; bi_[K - 1] = j;
            #pragma unroll
            for (int q = K - 1; q > 0; --q) {
                bool sw = (bd[q] < bd[q - 1]) || (bd[q] == bd[q - 1] && bi_[q] < bi_[q - 1]);
                if (sw) {
                    float td = bd[q]; bd[q] = bd[q - 1]; bd[q - 1] = td;
                    int   ti = bi_[q]; bi_[q] = bi_[q - 1]; bi_[q - 1] = ti;
                }
            }
        }
    }
    #pragma unroll
    for (int q = 0; q < K; ++q) nb_l[t + tstride * q] = bi_[q];
}

// ---------------------------------------------------------------------------
// MLP (DIN=131) accumulate-max for one neighbor: all-register, no LDS, no
// barriers. o-part is c-halved to cap VGPR pressure (~a64+o32+acc64).
// ---------------------------------------------------------------------------
__device__ __forceinline__ void mlp131_acc(const float* __restrict__ hi,
                                           const float* __restrict__ hj,
                                           float rx, float ry, float rz,
                                           const float* __restrict__ W1,
                                           const float* __restrict__ b1,
                                           const float* __restrict__ W2,
                                           const float* __restrict__ b2,
                                           float acc[64]) {
    float a[64];
    #pragma unroll
    for (int e = 0; e < 64; ++e) a[e] = b1[e];
    for (int d4 = 0; d4 < 16; ++d4) {
        float4 v = *(const float4*)(hi + d4 * 4);
        const float mu[4] = {v.x, v.y, v.z, v.w};
        const float* wr = W1 + (size_t)(d4 * 4) * 64;
        #pragma unroll
        for (int u = 0; u < 4; ++u) {
            #pragma unroll
            for (int e = 0; e < 64; ++e) a[e] = fmaf(mu[u], wr[u * 64 + e], a[e]);
        }
    }
    for (int d4 = 0; d4 < 16; ++d4) {
        float4 v = *(const float4*)(hj + d4 * 4);
        const float mu[4] = {v.x, v.y, v.z, v.w};
        const float* wr = W1 + (size_t)(64 + d4 * 4) * 64;
        #pragma unroll
        for (int u = 0; u < 4; ++u) {
            #pragma unroll
            for (int e = 0; e < 64; ++e) a[e] = fmaf(mu[u], wr[u * 64 + e], a[e]);
        }
    }
    {
        const float mr[3] = {rx, ry, rz};
        #pragma unroll
        for (int d = 0; d < 3; ++d) {
            #pragma unroll
            for (int e = 0; e < 64; ++e) a[e] = fmaf(mr[d], W1[(128 + d) * 64 + e], a[e]);
        }
    }
    #pragma unroll
    for (int h = 0; h < 2; ++h) {
        float o[32];
        #pragma unroll
        for (int c = 0; c < 32; ++c) o[c] = b2[h * 32 + c];
        #pragma unroll
        for (int e = 0; e < 64; ++e) {
            float av = fmaxf(a[e], 0.f);
            #pragma unroll
            for (int c = 0; c < 32; ++c) o[c] = fmaf(av, W2[e * 64 + h * 32 + c], o[c]);
        }
        #pragma unroll
        for (int c = 0; c < 32; ++c) acc[h * 32 + c] = fmaxf(acc[h * 32 + c], o[c]);
    }
}

// ---------------------------------------------------------------------------
// FRONT: blocks [0,B) = chained FPS (2048->1024->512) with DPP argmax;
// blocks [B, B+256) = fused knn6 + pointnet layer 1 -> h1.
// ---------------------------------------------------------------------------
__global__ void __launch_bounds__(256) front_kernel(
        const float* __restrict__ posf,
        const float* __restrict__ W1, const float* __restrict__ b1,
        const float* __restrict__ W2, const float* __restrict__ b2,
        float* __restrict__ h1, int* __restrict__ sel1, int* __restrict__ sel2,
        float* __restrict__ p2, float* __restrict__ p3) {
    __shared__ __align__(16) char smem[43136];
    const int t = threadIdx.x;

    if (blockIdx.x < B) {
        __builtin_amdgcn_s_setprio(1);
        const int b = blockIdx.x;
        float* px = (float*)smem;               // 2048
        float* py = px + 2048;
        float* pz = py + 2048;
        int*   sel1_l = (int*)(pz + 2048);      // 1024
        float* qx = (float*)(sel1_l + 1024);    // 1024
        float* qy = qx + 1024;
        float* qz = qy + 1024;
        int*   sel2_l = (int*)(qz + 1024);      // 512
        unsigned long long* slots = (unsigned long long*)(sel2_l + 512);  // 8

        const float* pb = posf + (size_t)b * N * 3;
        for (int i = t; i < N; i += 256) {
            px[i] = pb[i * 3 + 0]; py[i] = pb[i * 3 + 1]; pz[i] = pb[i * 3 + 2];
        }
        __syncthreads();

        fps_phase<2048>(px, py, pz, sel1_l, slots, 1024, t);

        for (int i = t; i < 1024; i += 256) {
            int s = sel1_l[i];
            qx[i] = px[s]; qy[i] = py[s]; qz[i] = pz[s];
            sel1[(size_t)b * 1024 + i] = s;
        }
        __syncthreads();
        for (int i = t; i < 1024; i += 256) {
            float* pp = p2 + ((size_t)b * 1024 + i) * 3;
            pp[0] = qx[i]; pp[1] = qy[i]; pp[2] = qz[i];
        }

        fps_phase<1024>(qx, qy, qz, sel2_l, slots, 512, t);

        for (int i = t; i < 512; i += 256) {
            int s = sel2_l[i];
            sel2[(size_t)b * 512 + i] = s;
            float* pp = p3 + ((size_t)b * 512 + i) * 3;
            pp[0] = qx[s]; pp[1] = qy[s]; pp[2] = qz[s];
        }
    } else {
        // ---------------- fused knn6 + pointnet layer 1 ----------------
        const int f = (int)blockIdx.x - B;
        const int b = f >> 3;
        const int i = ((f & 7) << 8) + t;       // point in [0,2048)
        float* cx = (float*)smem;               // 2048
        float* cy = cx + 2048;
        float* cz = cy + 2048;
        int*   nb_l = (int*)(cz + 2048);        // 256*6 ints = 6 KB

        const float* pb = posf + (size_t)b * N * 3;
        for (int j = t; j < N; j += 256) {
            cx[j] = pb[j * 3 + 0]; cy[j] = pb[j * 3 + 1]; cz[j] = pb[j * 3 + 2];
        }
        __syncthreads();
        const float xi = cx[i], yi = cy[i], zi = cz[i];
        knn_lds<6>(cx, cy, cz, N, xi, yi, zi, nb_l, t, 256);

        float acc[64];
        #pragma unroll
        for (int c = 0; c < 64; ++c) acc[c] = -__builtin_inff();

        for (int kk = 0; kk < 6; ++kk) {
            const int j = nb_l[t + 256 * kk];
            const float xj = cx[j], yj = cy[j], zj = cz[j];
            const float mv[9] = {xi, yi, zi, xj, yj, zj, xj - xi, yj - yi, zj - zi};
            float a[64];
            #pragma unroll
            for (int e = 0; e < 64; ++e) a[e] = b1[e];
            #pragma unroll
            for (int d = 0; d < 9; ++d) {
                #pragma unroll
                for (int e = 0; e < 64; ++e) a[e] = fmaf(mv[d], W1[d * 64 + e], a[e]);
            }
            #pragma unroll
            for (int h = 0; h < 2; ++h) {
                float o[32];
                #pragma unroll
                for (int c = 0; c < 32; ++c) o[c] = b2[h * 32 + c];
                #pragma unroll
                for (int e = 0; e < 64; ++e) {
                    float av = fmaxf(a[e], 0.f);
                    #pragma unroll
                    for (int c = 0; c < 32; ++c) o[c] = fmaf(av, W2[e * 64 + h * 32 + c], o[c]);
                }
                #pragma unroll
                for (int c = 0; c < 32; ++c) acc[h * 32 + c] = fmaxf(acc[h * 32 + c], o[c]);
            }
        }
        float* op = h1 + ((size_t)b * N + i) * 64;
        #pragma unroll
        for (int c = 0; c < 64; ++c) op[c] = fmaxf(acc[c], 0.f);
    }
}

// ---------------------------------------------------------------------------
// LAYER 2: fused knn4 + pointnet (DIN=131). h gathered from h1 via sel1
// indirection (no materialized h2in / idx2). 4 blocks per graph.
// ---------------------------------------------------------------------------
__global__ void __launch_bounds__(256) layer2_kernel(
        const float* __restrict__ h1, const float* __restrict__ p2,
        const int* __restrict__ sel1,
        const float* __restrict__ W1, const float* __restrict__ b1,
        const float* __restrict__ W2, const float* __restrict__ b2,
        float* __restrict__ h2out) {
    __shared__ float qx[1024], qy[1024], qz[1024];
    __shared__ int nb_l[256 * 4];
    const int t = threadIdx.x;
    const int b = blockIdx.x >> 2;
    const int i = ((blockIdx.x & 3) << 8) + t;   // point in [0,1024)

    const float* pb = p2 + (size_t)b * 1024 * 3;
    for (int j = t; j < 1024; j += 256) {
        qx[j] = pb[j * 3 + 0]; qy[j] = pb[j * 3 + 1]; qz[j] = pb[j * 3 + 2];
    }
    __syncthreads();
    const float xi = qx[i], yi = qy[i], zi = qz[i];
    knn_lds<4>(qx, qy, qz, 1024, xi, yi, zi, nb_l, t, 256);

    const int s1i = sel1[(size_t)b * 1024 + i];
    const float* hi = h1 + ((size_t)b * N + s1i) * 64;

    float acc[64];
    #pragma unroll
    for (int c = 0; c < 64; ++c) acc[c] = -__builtin_inff();

    for (int kk = 0; kk < 4; ++kk) {
        const int j = nb_l[t + 256 * kk];
        const int s1j = sel1[(size_t)b * 1024 + j];
        const float* hj = h1 + ((size_t)b * N + s1j) * 64;
        mlp131_acc(hi, hj, qx[j] - xi, qy[j] - yi, qz[j] - zi, W1, b1, W2, b2, acc);
    }
    float* op = h2out + ((size_t)b * 1024 + i) * 64;
    #pragma unroll
    for (int c = 0; c < 64; ++c) op[c] = fmaxf(acc[c], 0.f);
}

// ---------------------------------------------------------------------------
// LAYER 3 + HEAD: one block per graph (512 threads = 512 points). knn3 +
// pointnet + in-block channel max (bitwise atomicMax valid: post-ReLU >= 0)
// + 64x6 head linear -> d_out.
// ---------------------------------------------------------------------------
__global__ void __launch_bounds__(512) layer3_kernel(
        const float* __restrict__ h2, const float* __restrict__ p3,
        const int* __restrict__ sel2,
        const float* __restrict__ W1, const float* __restrict__ b1,
        const float* __restrict__ W2, const float* __restrict__ b2,
        const float* __restrict__ Wr, const float* __restrict__ br,
        void* __restrict__ out, const int* __restrict__ flag) {
    __shared__ float qx[512], qy[512], qz[512];
    __shared__ int nb_l[512 * 3];
    __shared__ int gbits[64];
    const int t = threadIdx.x;
    const int b = blockIdx.x;

    const float* pb = p3 + (size_t)b * 512 * 3;
    if (t < 512) { qx[t] = pb[t * 3 + 0]; qy[t] = pb[t * 3 + 1]; qz[t] = pb[t * 3 + 2]; }
    if (t < 64) gbits[t] = 0;
    __syncthreads();
    const float xi = qx[t], yi = qy[t], zi = qz[t];
    knn_lds<3>(qx, qy, qz, 512, xi, yi, zi, nb_l, t, 512);

    const int s2i = sel2[(size_t)b * 512 + t];
    const float* hi = h2 + ((size_t)b * 1024 + s2i) * 64;

    float acc[64];
    #pragma unroll
    for (int c = 0; c < 64; ++c) acc[c] = -__builtin_inff();

    for (int kk = 0; kk < 3; ++kk) {
        const int j = nb_l[t + 512 * kk];
        const int s2j = sel2[(size_t)b * 512 + j];
        const float* hj = h2 + ((size_t)b * 1024 + s2j) * 64;
        mlp131_acc(hi, hj, qx[j] - xi, qy[j] - yi, qz[j] - zi, W1, b1, W2, b2, acc);
    }
    #pragma unroll
    for (int c = 0; c < 64; ++c) {
        atomicMax(&gbits[c], __float_as_int(fmaxf(acc[c], 0.f)));
    }
    __syncthreads();
    if (t < 6) {
        float o = br[t];
        #pragma unroll
        for (int c = 0; c < 64; ++c) o = fmaf(__int_as_float(gbits[c]), Wr[c * 6 + t], o);
        if (*flag) ((__hip_bfloat16*)out)[b * 6 + t] = __float2bfloat16(o);
        else       ((float*)out)[b * 6 + t] = o;
    }
}

// ---------------------------------------------------------------------------
extern "C" void kernel_launch(void* const* d_in, const int* in_sizes, int n_in,
                              void* d_out, int out_size, void* d_ws, size_t ws_size,
                              hipStream_t stream) {
    (void)in_sizes; (void)n_in; (void)out_size; (void)ws_size;

    char* w = (char*)d_ws;
    auto alloc = [&](size_t nbytes) -> void* {
        void* p = (void*)w;
        w += (nbytes + 255) & ~(size_t)255;
        return p;
    };

    int*   flag = (int*)alloc(4);
    float* posf = (float*)alloc((size_t)B * N * 3 * 4);
    float* W1a = (float*)alloc(9 * 64 * 4);    float* b1a = (float*)alloc(64 * 4);
    float* W1b = (float*)alloc(64 * 64 * 4);   float* b1b = (float*)alloc(64 * 4);
    float* W2a = (float*)alloc(131 * 64 * 4);  float* b2a = (float*)alloc(64 * 4);
    float* W2b = (float*)alloc(64 * 64 * 4);   float* b2b = (float*)alloc(64 * 4);
    float* W3a = (float*)alloc(131 * 64 * 4);  float* b3a = (float*)alloc(64 * 4);
    float* W3b = (float*)alloc(64 * 64 * 4);   float* b3b = (float*)alloc(64 * 4);
    float* Wr  = (float*)alloc(64 * 6 * 4);    float* br  = (float*)alloc(6 * 4);

    float* h1    = (float*)alloc((size_t)B * N * 64 * 4);        // 16 MB
    float* h2out = (float*)alloc((size_t)B * 1024 * 64 * 4);     // 8 MB
    int*   sel1  = (int*)alloc((size_t)B * 1024 * 4);
    int*   sel2  = (int*)alloc((size_t)B * 512 * 4);
    float* p2    = (float*)alloc((size_t)B * 1024 * 3 * 4);
    float* p3    = (float*)alloc((size_t)B * 512 * 3 * 4);

    // --- dtype detect + convert to fp32 ---
    detect_kernel<<<dim3(1), 256, 0, stream>>>((const unsigned int*)d_in[1], flag);
    ConvParams cp;
    {
        float* wd[15] = {posf, W1a, b1a, W1b, b1b, W2a, b2a, W2b, b2b, W3a, b3a, W3b, b3b, Wr, br};
        const int wi[15] = {1, 3, 4, 5, 6, 7, 8, 9, 10, 11, 12, 13, 14, 15, 16};
        const int wn[15] = {B * N * 3, 576, 64, 4096, 64, 8384, 64, 4096, 64, 8384, 64, 4096, 64, 384, 6};
        for (int q = 0; q < 15; ++q) { cp.s[q].src = d_in[wi[q]]; cp.s[q].dst = wd[q]; cp.s[q].n = wn[q]; }
    }
    convert_kernel<<<dim3((B * N * 3 + 255) / 256, 15), 256, 0, stream>>>(cp, flag);

    // --- front: FPS chain (32 blocks) + knn6/pointnet1 (256 blocks) ---
    front_kernel<<<dim3(B + 256), 256, 0, stream>>>(posf, W1a, b1a, W1b, b1b,
                                                    h1, sel1, sel2, p2, p3);

    // --- layer 2: fused knn4 + pointnet ---
    layer2_kernel<<<dim3(128), 256, 0, stream>>>(h1, p2, sel1, W2a, b2a, W2b, b2b, h2out);

    // --- layer 3 + head ---
    layer3_kernel<<<dim3(B), 512, 0, stream>>>(h2out, p3, sel2, W3a, b3a, W3b, b3b,
                                               Wr, br, d_out, flag);
}